// Round 7
// baseline (450.225 us; speedup 1.0000x reference)
//
#include <hip/hip_runtime.h>

#define ROW_N 2048
#define ROW_K 1024          // zero the 1024 smallest per row
#define NSUB 4              // round-0 sub-histograms (lane & 3)
#define HPAD 264            // 256 bins + 8 pad -> sub s staggered by 8 banks
#define WH   (NSUB * HPAD)  // 1056 dwords of round-0 histogram per wave
#define WSTRIDE (WH + 4)    // +4 dword stagger between waves

// Wave-local LDS fence: all of this wave's ds ops drained.
__device__ __forceinline__ void wfence() {
    asm volatile("s_waitcnt lgkmcnt(0)" ::: "memory");
}

// Monotone bijection float -> uint32 (order-preserving, invertible).
__device__ __forceinline__ unsigned f2key(float x) {
    unsigned u = __float_as_uint(x);
    return u ^ ((unsigned)((int)u >> 31) | 0x80000000u);
}
__device__ __forceinline__ float key2f(unsigned k) {
    unsigned u = (k & 0x80000000u) ? (k ^ 0x80000000u) : ~k;
    return __uint_as_float(u);
}

// Scan 256 bins (4/lane), locate rank; broadcast {digit,cnteq,rank} packed
// in ONE shuffle. beq,rr <= 2048 fit 12 bits; d fits 8.
__device__ __forceinline__ void scan_pick(unsigned b0, unsigned b1, unsigned b2,
                                          unsigned b3, int lane, int rank_in,
                                          unsigned& digit, int& rank_out,
                                          int& cnteq_out) {
    unsigned s4 = b0 + b1 + b2 + b3;
    unsigned incl = s4;
#pragma unroll
    for (int off = 1; off < 64; off <<= 1) {
        unsigned n = __shfl_up(incl, off, 64);
        if (lane >= off) incl += n;
    }
    int excl = (int)(incl - s4);
    bool found = (rank_in >= excl) && (rank_in < (int)incl);
    int rr = rank_in - excl;
    unsigned d = 4 * lane;
    unsigned beq = b0;
    if (found) {
        if (rr >= (int)b0) { rr -= (int)b0; d++; beq = b1;
            if (rr >= (int)b1) { rr -= (int)b1; d++; beq = b2;
                if (rr >= (int)b2) { rr -= (int)b2; d++; beq = b3; } } }
    }
    unsigned pack = (d << 24) | (beq << 12) | (unsigned)rr;
    unsigned long long bal = __ballot(found);
    int src = __builtin_ctzll(bal);          // exactly one lane found
    pack = (unsigned)__shfl((int)pack, src, 64);
    digit = pack >> 24;
    cnteq_out = (int)((pack >> 12) & 0xfffu);
    rank_out = (int)(pack & 0xfffu);
}

__global__ __launch_bounds__(256, 8)
void ktakes_kernel(const float* __restrict__ g, float* __restrict__ out) {
    const int tid  = threadIdx.x;
    const int wave = tid >> 6;
    const int lane = tid & 63;
    const int row  = blockIdx.x * 4 + wave;

    __shared__ unsigned H[4 * WSTRIDE];
    unsigned* hw   = H + wave * WSTRIDE;
    uint4*    hw4  = reinterpret_cast<uint4*>(hw);
    unsigned* hsub = hw + (lane & (NSUB - 1)) * HPAD;

    const float4* g4 = reinterpret_cast<const float4*>(g + (size_t)row * ROW_N);
    float4*       o4 = reinterpret_cast<float4*>(out + (size_t)row * ROW_N);

    // ---- load full row: 32 keys/lane, coalesced float4 ----
    unsigned k[32];
#pragma unroll
    for (int j = 0; j < 8; ++j) {
        float4 v = g4[j * 64 + lane];            // element idx 256j + 4*lane + c
        k[4*j+0] = f2key(v.x); k[4*j+1] = f2key(v.y);
        k[4*j+2] = f2key(v.z); k[4*j+3] = f2key(v.w);
    }

    const uint4 z4 = {0u, 0u, 0u, 0u};
    unsigned prefix;
    int rank, cnteq;

    // ================= ROUND 0 (8-bit MSB, 4 sub-histograms) =================
    {
#pragma unroll
        for (int i = 0; i < 4; ++i) hw4[i * 64 + lane] = z4;   // dwords 0..1023
        if (lane < 32) hw[1024 + lane] = 0;                     // 1024..1055
        wfence();
#pragma unroll
        for (int c = 0; c < 32; ++c)
            atomicAdd(&hsub[k[c] >> 24], 1u);
        wfence();
        // accumulate 4 subs sequentially (low live-reg pressure)
        unsigned b0 = 0, b1 = 0, b2 = 0, b3 = 0;
#pragma unroll
        for (int s = 0; s < NSUB; ++s) {
            uint4 h = *reinterpret_cast<const uint4*>(&hw[s * HPAD + 4 * lane]);
            b0 += h.x; b1 += h.y; b2 += h.z; b3 += h.w;
        }
        wfence();
        unsigned d;
        scan_pick(b0, b1, b2, b3, lane, ROW_K - 1, d, rank, cnteq);
        prefix = d << 24;
    }

    // ============ ROUNDS 1..3 (8 bits each, single histogram) ============
#pragma unroll
    for (int r = 1; r < 4; ++r) {
        const int shift = 24 - 8 * r;
        const int hs = shift + 8;

        hw4[lane] = z4;                          // zero bins 0..255
        wfence();
#pragma unroll
        for (int c = 0; c < 32; ++c)
            if (((k[c] ^ prefix) >> hs) == 0)
                atomicAdd(&hw[(k[c] >> shift) & 255u], 1u);
        wfence();
        uint4 h = hw4[lane];
        wfence();
        unsigned d;
        scan_pick(h.x, h.y, h.z, h.w, lane, rank, d, rank, cnteq);
        prefix |= d << shift;
    }

    const unsigned Kth = prefix;    // key at ascending rank 1023
    const int m = rank + 1;         // # of ==Kth elems to zero (lowest index first)

    // ---- build zero-mask ----
    unsigned zm = 0;
    if (cnteq == m) {
#pragma unroll
        for (int c = 0; c < 32; ++c)
            if (k[c] <= Kth) zm |= 1u << c;
    } else {
        // rare tie path: zero only first m equals in global index order
        int base = 0;
#pragma unroll
        for (int j = 0; j < 8; ++j) {
            int eqmask = 0, e = 0;
#pragma unroll
            for (int c = 0; c < 4; ++c) {
                bool q = (k[4*j+c] == Kth);
                eqmask |= (int)q << c; e += (int)q;
            }
            int incl = e;
#pragma unroll
            for (int off = 1; off < 64; off <<= 1) {
                int n = __shfl_up(incl, off, 64);
                if (lane >= off) incl += n;
            }
            int excl = incl - e;
            int tot = __shfl(incl, 63, 64);
            int pos = base + excl;               // index order = (j, lane, c)
#pragma unroll
            for (int c = 0; c < 4; ++c) {
                if (eqmask & (1 << c)) {
                    if (pos < m) zm |= 1u << (4*j+c);
                    pos++;
                }
            }
            base += tot;
        }
#pragma unroll
        for (int c = 0; c < 32; ++c)
            if (k[c] < Kth) zm |= 1u << c;
    }

    // ---- write output (reconstruct floats from keys) ----
#pragma unroll
    for (int j = 0; j < 8; ++j) {
        float4 v;
        v.x = (zm >> (4*j+0)) & 1u ? 0.0f : key2f(k[4*j+0]);
        v.y = (zm >> (4*j+1)) & 1u ? 0.0f : key2f(k[4*j+1]);
        v.z = (zm >> (4*j+2)) & 1u ? 0.0f : key2f(k[4*j+2]);
        v.w = (zm >> (4*j+3)) & 1u ? 0.0f : key2f(k[4*j+3]);
        o4[j * 64 + lane] = v;
    }
}

extern "C" void kernel_launch(void* const* d_in, const int* in_sizes, int n_in,
                              void* d_out, int out_size, void* d_ws, size_t ws_size,
                              hipStream_t stream) {
    const float* g = (const float*)d_in[0];
    float* out = (float*)d_out;
    const int rows = in_sizes[0] / ROW_N;     // 32768, divisible by 4
    hipLaunchKernelGGL(ktakes_kernel, dim3(rows / 4), dim3(256), 0, stream, g, out);
}

// Round 8
// 430.521 us; speedup vs baseline: 1.0458x; 1.0458x over previous
//
#include <hip/hip_runtime.h>

#define ROW_N 2048
#define ROW_K 1024          // zero the 1024 smallest per row
#define HPAD  264           // 256 bins + 8-dword stagger between the 2 subs
#define BUFA  528           // rounds 1&3 histogram (256 dwords)
#define BUFB  784           // round 2 histogram (256 dwords)
#define WHTOT 1040          // dwords of LDS per wave actually used
#define WSTRIDE 1048        // +8 dword stagger between waves (keeps 16B align)

// Wave-local LDS fence: this wave's ds ops drained. Does NOT wait on vmcnt.
__device__ __forceinline__ void wfence() {
    asm volatile("s_waitcnt lgkmcnt(0)" ::: "memory");
}

// Monotone bijection float -> uint32 (order-preserving, invertible).
__device__ __forceinline__ unsigned f2key(float x) {
    unsigned u = __float_as_uint(x);
    return u ^ ((unsigned)((int)u >> 31) | 0x80000000u);
}
__device__ __forceinline__ float key2f(unsigned k) {
    unsigned u = (k & 0x80000000u) ? (k ^ 0x80000000u) : ~k;
    return __uint_as_float(u);
}

// 64-lane inclusive add-scan, pure VALU (DPP), no LDS traffic.
// Canonical gfx9 sequence: after shr1/2/4/8 each 16-lane row holds its own
// inclusive scan; bcast15 (row_mask 0xa) adds lane15->16..31 and lane47->48..63;
// bcast31 (row_mask 0xc) adds lane31 (=rows0+1 total) -> lanes 32..63.
__device__ __forceinline__ unsigned wave_incl_scan(unsigned x) {
    int v = (int)x;
    v += __builtin_amdgcn_update_dpp(0, v, 0x111, 0xf, 0xf, false); // row_shr:1
    v += __builtin_amdgcn_update_dpp(0, v, 0x112, 0xf, 0xf, false); // row_shr:2
    v += __builtin_amdgcn_update_dpp(0, v, 0x114, 0xf, 0xf, false); // row_shr:4
    v += __builtin_amdgcn_update_dpp(0, v, 0x118, 0xf, 0xf, false); // row_shr:8
    v += __builtin_amdgcn_update_dpp(0, v, 0x142, 0xa, 0xf, false); // row_bcast:15
    v += __builtin_amdgcn_update_dpp(0, v, 0x143, 0xc, 0xf, false); // row_bcast:31
    return (unsigned)v;
}

// Scan 256 bins (4/lane), locate rank; broadcast {digit,cnteq,rank} packed
// via SALU readlane (no DS). beq,rr <= 2048 fit 12 bits; d fits 8.
__device__ __forceinline__ void scan_pick(unsigned b0, unsigned b1, unsigned b2,
                                          unsigned b3, int lane, int rank_in,
                                          unsigned& digit, int& rank_out,
                                          int& cnteq_out) {
    unsigned s4 = b0 + b1 + b2 + b3;
    unsigned incl = wave_incl_scan(s4);
    int excl = (int)(incl - s4);
    bool found = (rank_in >= excl) && (rank_in < (int)incl);
    int rr = rank_in - excl;
    unsigned d = 4 * lane;
    unsigned beq = b0;
    if (found) {
        if (rr >= (int)b0) { rr -= (int)b0; d++; beq = b1;
            if (rr >= (int)b1) { rr -= (int)b1; d++; beq = b2;
                if (rr >= (int)b2) { rr -= (int)b2; d++; beq = b3; } } }
    }
    unsigned pack = (d << 24) | (beq << 12) | (unsigned)rr;
    unsigned long long bal = __ballot(found);
    int src = (int)__builtin_ctzll(bal);            // exactly one lane found
    pack = (unsigned)__builtin_amdgcn_readlane((int)pack, src);
    digit = pack >> 24;
    cnteq_out = (int)((pack >> 12) & 0xfffu);
    rank_out = (int)(pack & 0xfffu);
}

__global__ __launch_bounds__(256)
void ktakes_kernel(const float* __restrict__ g, float* __restrict__ out) {
    const int tid  = threadIdx.x;
    const int wave = tid >> 6;
    const int lane = tid & 63;
    const int row  = blockIdx.x * 4 + wave;

    __shared__ unsigned H[4 * WSTRIDE];
    unsigned* hw   = H + wave * WSTRIDE;
    uint4*    hw4  = reinterpret_cast<uint4*>(hw);
    unsigned* hsub = hw + (lane & 1) * HPAD;        // round-0: 2 staggered subs

    const float4* g4 = reinterpret_cast<const float4*>(g + (size_t)row * ROW_N);
    float4*       o4 = reinterpret_cast<float4*>(out + (size_t)row * ROW_N);

    // ---- issue all 8 global loads; zero ALL histograms under the vmcnt window
    // (zero is lgkm — independent counter, hides under HBM latency) ----
    const uint4 z4 = {0u, 0u, 0u, 0u};
#pragma unroll
    for (int i = 0; i < 4; ++i) hw4[i * 64 + lane] = z4;    // dwords 0..1023
    if (lane < 16) hw[1024 + lane] = 0;                     // 1024..1039

    unsigned k[32];
#pragma unroll
    for (int j = 0; j < 8; ++j) {
        float4 v = g4[j * 64 + lane];            // element idx 256j + 4*lane + c
        k[4*j+0] = f2key(v.x); k[4*j+1] = f2key(v.y);
        k[4*j+2] = f2key(v.z); k[4*j+3] = f2key(v.w);
    }

    unsigned prefix;
    int rank, cnteq;
    unsigned d;

    // ================= ROUND 0 (bits 31..24, 2 staggered subs) ===============
    wfence();                                    // zeros drained (long since)
#pragma unroll
    for (int c = 0; c < 32; ++c)
        atomicAdd(&hsub[k[c] >> 24], 1u);
    wfence();
    {
        uint4 h0 = *reinterpret_cast<const uint4*>(&hw[4 * lane]);
        uint4 h1 = *reinterpret_cast<const uint4*>(&hw[HPAD + 4 * lane]);
        scan_pick(h0.x + h1.x, h0.y + h1.y, h0.z + h1.z, h0.w + h1.w,
                  lane, ROW_K - 1, d, rank, cnteq);
        prefix = d << 24;
    }

    // ================= ROUND 1 (bits 23..16, buffer A) =======================
#pragma unroll
    for (int c = 0; c < 32; ++c)
        if (((k[c] ^ prefix) >> 24) == 0)
            atomicAdd(&hw[BUFA + ((k[c] >> 16) & 255u)], 1u);
    wfence();
    {
        uint4 h = *reinterpret_cast<const uint4*>(&hw[BUFA + 4 * lane]);
        scan_pick(h.x, h.y, h.z, h.w, lane, rank, d, rank, cnteq);
        prefix |= d << 16;
    }

    // ================= ROUND 2 (bits 15..8, buffer B; re-zero A) =============
#pragma unroll
    for (int c = 0; c < 32; ++c)
        if (((k[c] ^ prefix) >> 16) == 0)
            atomicAdd(&hw[BUFB + ((k[c] >> 8) & 255u)], 1u);
    // A's round-1 values were consumed (lgkm-waited) in scan_pick; safe to re-zero
    *reinterpret_cast<uint4*>(&hw[BUFA + 4 * lane]) = z4;
    wfence();
    {
        uint4 h = *reinterpret_cast<const uint4*>(&hw[BUFB + 4 * lane]);
        scan_pick(h.x, h.y, h.z, h.w, lane, rank, d, rank, cnteq);
        prefix |= d << 8;
    }

    // ================= ROUND 3 (bits 7..0, buffer A) =========================
#pragma unroll
    for (int c = 0; c < 32; ++c)
        if (((k[c] ^ prefix) >> 8) == 0)
            atomicAdd(&hw[BUFA + (k[c] & 255u)], 1u);
    wfence();
    {
        uint4 h = *reinterpret_cast<const uint4*>(&hw[BUFA + 4 * lane]);
        scan_pick(h.x, h.y, h.z, h.w, lane, rank, d, rank, cnteq);
        prefix |= d;
    }

    const unsigned Kth = prefix;    // key at ascending rank 1023
    const int m = rank + 1;         // # of ==Kth elems to zero (lowest index first)

    // ---- build zero-mask ----
    unsigned zm = 0;
    if (cnteq == m) {
#pragma unroll
        for (int c = 0; c < 32; ++c)
            if (k[c] <= Kth) zm |= 1u << c;
    } else {
        // rare tie path: zero only first m equals in global index order
        int base = 0;
#pragma unroll
        for (int j = 0; j < 8; ++j) {
            int eqmask = 0, e = 0;
#pragma unroll
            for (int c = 0; c < 4; ++c) {
                bool q = (k[4*j+c] == Kth);
                eqmask |= (int)q << c; e += (int)q;
            }
            int incl = e;
#pragma unroll
            for (int off = 1; off < 64; off <<= 1) {
                int n = __shfl_up(incl, off, 64);
                if (lane >= off) incl += n;
            }
            int excl = incl - e;
            int tot = __shfl(incl, 63, 64);
            int pos = base + excl;               // index order = (j, lane, c)
#pragma unroll
            for (int c = 0; c < 4; ++c) {
                if (eqmask & (1 << c)) {
                    if (pos < m) zm |= 1u << (4*j+c);
                    pos++;
                }
            }
            base += tot;
        }
#pragma unroll
        for (int c = 0; c < 32; ++c)
            if (k[c] < Kth) zm |= 1u << c;
    }

    // ---- write output (reconstruct floats from keys) ----
#pragma unroll
    for (int j = 0; j < 8; ++j) {
        float4 v;
        v.x = (zm >> (4*j+0)) & 1u ? 0.0f : key2f(k[4*j+0]);
        v.y = (zm >> (4*j+1)) & 1u ? 0.0f : key2f(k[4*j+1]);
        v.z = (zm >> (4*j+2)) & 1u ? 0.0f : key2f(k[4*j+2]);
        v.w = (zm >> (4*j+3)) & 1u ? 0.0f : key2f(k[4*j+3]);
        o4[j * 64 + lane] = v;
    }
}

extern "C" void kernel_launch(void* const* d_in, const int* in_sizes, int n_in,
                              void* d_out, int out_size, void* d_ws, size_t ws_size,
                              hipStream_t stream) {
    const float* g = (const float*)d_in[0];
    float* out = (float*)d_out;
    const int rows = in_sizes[0] / ROW_N;     // 32768, divisible by 4
    hipLaunchKernelGGL(ktakes_kernel, dim3(rows / 4), dim3(256), 0, stream, g, out);
}